// Round 8
// baseline (454.571 us; speedup 1.0000x reference)
//
#include <hip/hip_runtime.h>

#define NN 100000
#define EE 1600000
#define NCOPY 8

typedef short bf16x8 __attribute__((ext_vector_type(8)));
typedef float floatx4 __attribute__((ext_vector_type(4)));

__device__ __forceinline__ unsigned short f2bf(float f) {
    unsigned int u = __float_as_uint(f);
    u = (u + 0x7FFF + ((u >> 16) & 1)) >> 16;   // round-to-nearest-even
    return (unsigned short)u;
}
__device__ __forceinline__ float bf2f_lo(unsigned int packed) {
    return __uint_as_float(packed << 16);
}
__device__ __forceinline__ float bf2f_hi(unsigned int packed) {
    return __uint_as_float(packed & 0xFFFF0000u);
}

// ---------------- setup kernels ----------------

__global__ void k_zero_int4(int4* __restrict__ p, int n4) {
    int i = blockIdx.x * 256 + threadIdx.x;
    if (i < n4) p[i] = make_int4(0, 0, 0, 0);
}

// Pass 1: rank within XCD-local copy (p = blockIdx&7). Returning atomics, but
// copies kill cross-XCD line ping-pong; rank store is coalesced write-only.
__global__ void k_count_rank8(const int* __restrict__ dst, int* __restrict__ cntp,
                              int* __restrict__ rank) {
    int e8 = (blockIdx.x * 256 + threadIdx.x) * 8;
    int* c = cntp + (blockIdx.x & (NCOPY - 1)) * NN;
    if (e8 < EE) {   // EE % 8 == 0
        int4 d0 = *(const int4*)&dst[e8];
        int4 d1 = *(const int4*)&dst[e8 + 4];
        int4 r0, r1;
        r0.x = atomicAdd(&c[d0.x], 1);
        r0.y = atomicAdd(&c[d0.y], 1);
        r0.z = atomicAdd(&c[d0.z], 1);
        r0.w = atomicAdd(&c[d0.w], 1);
        r1.x = atomicAdd(&c[d1.x], 1);
        r1.y = atomicAdd(&c[d1.y], 1);
        r1.z = atomicAdd(&c[d1.z], 1);
        r1.w = atomicAdd(&c[d1.w], 1);
        *(int4*)&rank[e8]     = r0;
        *(int4*)&rank[e8 + 4] = r1;
    }
}

// scan1 (fused with old sumcnt): per-node copy-prefix + block-level exclusive
// scan of totals; block totals -> S.
__global__ __launch_bounds__(1024) void k_scan1(int* __restrict__ cntp,
                                                int* __restrict__ cnt,
                                                int* __restrict__ row_ptr,
                                                int* __restrict__ S) {
    __shared__ int sh[1024];
    int tid = threadIdx.x;
    int i = blockIdx.x * 1024 + tid;
    int v = 0;
    if (i < NN) {
        int s = 0;
#pragma unroll
        for (int p = 0; p < NCOPY; p++) {
            int t = cntp[p * NN + i];
            cntp[p * NN + i] = s;    // within-node prefix across copies
            s += t;
        }
        cnt[i] = s;
        v = s;
    }
    sh[tid] = v;
    __syncthreads();
    for (int off = 1; off < 1024; off <<= 1) {
        int t = (tid >= off) ? sh[tid - off] : 0;
        __syncthreads();
        sh[tid] += t;
        __syncthreads();
    }
    if (i < NN) row_ptr[i] = sh[tid] - v;       // exclusive
    if (tid == 1023) S[blockIdx.x] = sh[tid];   // block total
}

// exclusive scan of the 98 block totals, one block
__global__ __launch_bounds__(128) void k_scan2(int* __restrict__ S, int nb) {
    __shared__ int sh[128];
    int tid = threadIdx.x;
    int v = (tid < nb) ? S[tid] : 0;
    sh[tid] = v;
    __syncthreads();
    for (int off = 1; off < 128; off <<= 1) {
        int t = (tid >= off) ? sh[tid - off] : 0;
        __syncthreads();
        sh[tid] += t;
        __syncthreads();
    }
    if (tid < nb) S[tid] = sh[tid] - v;
}

// finalize: rc pack, dis, fold absolute row_ptr into the 8 copy base cursors,
// zero row NN of A.
__global__ void k_scan3(const int* __restrict__ row_ptr, int2* __restrict__ rc,
                        const int* __restrict__ S, const int* __restrict__ cnt,
                        float* __restrict__ dis, int* __restrict__ cntp,
                        unsigned int* __restrict__ Azero) {
    int i = blockIdx.x * 256 + threadIdx.x;
    if (i < NN) {
        int c = cnt[i];
        int r = row_ptr[i] + S[i >> 10];
        rc[i] = make_int2(r, c);
        dis[i] = rsqrtf((float)(c + 1));
#pragma unroll
        for (int p = 0; p < NCOPY; p++) cntp[p * NN + i] += r;  // absolute base cursors
    }
    if (blockIdx.x == 0 && threadIdx.x < 64) Azero[threadIdx.x] = 0;  // 256B zero row
}

// Pass 3: place with NO atomics. slot = cpre[p][d] (plain gather) + rank[e].
// Same grid/thread->edge mapping as pass 1 guarantees p(e) matches.
__global__ void k_fill4(const int* __restrict__ src, const int* __restrict__ dst,
                        const int* __restrict__ rank, const int* __restrict__ cntp,
                        int* __restrict__ csr) {
    int e8 = (blockIdx.x * 256 + threadIdx.x) * 8;
    const int* c = cntp + (blockIdx.x & (NCOPY - 1)) * NN;
    if (e8 < EE) {
        int4 s0 = *(const int4*)&src[e8];
        int4 s1 = *(const int4*)&src[e8 + 4];
        int4 d0 = *(const int4*)&dst[e8];
        int4 d1 = *(const int4*)&dst[e8 + 4];
        int4 r0 = *(const int4*)&rank[e8];
        int4 r1 = *(const int4*)&rank[e8 + 4];
        csr[c[d0.x] + r0.x] = s0.x;
        csr[c[d0.y] + r0.y] = s0.y;
        csr[c[d0.z] + r0.z] = s0.z;
        csr[c[d0.w] + r0.w] = s0.w;
        csr[c[d1.x] + r1.x] = s1.x;
        csr[c[d1.y] + r1.y] = s1.y;
        csr[c[d1.z] + r1.z] = s1.z;
        csr[c[d1.w] + r1.w] = s1.w;
    }
}

// all three weight matrices fp32->bf16 in one launch (quad-granular)
__global__ void k_cvt_w(const float* __restrict__ W1, const float* __restrict__ W2,
                        const float* __restrict__ WL,
                        unsigned short* __restrict__ W1b, unsigned short* __restrict__ W2b,
                        unsigned short* __restrict__ WLb) {
    int i = blockIdx.x * 256 + threadIdx.x;   // quad index
    const float* src; unsigned short* dst; int off;
    if (i < 4096)       { src = W1; dst = W1b; off = i; }
    else if (i < 8192)  { src = W2; dst = W2b; off = i - 4096; }
    else if (i < 10240) { src = WL; dst = WLb; off = i - 8192; }
    else return;
    float4 f = ((const float4*)src)[off];
    unsigned short r0 = f2bf(f.x), r1 = f2bf(f.y), r2 = f2bf(f.z), r3 = f2bf(f.w);
    ((ushort2*)dst)[off * 2]     = make_ushort2(r0, r1);
    ((ushort2*)dst)[off * 2 + 1] = make_ushort2(r2, r3);
}

// ---------------- MFMA GEMM: C[M,F] = A[M,128] @ W[F,128].T -------------------
// Optionally scales output rows by scale[row] (folds dis[src] into messages).
// Layouts (learn_hip m89): A[m=lane&15][k=quad*8+j], B[n=lane&15][k=quad*8+j],
// C/D col=lane&15 row=quad*4+reg.

template <int F, bool A_F32, bool OUT_BF16, bool SCALE>
__global__ __launch_bounds__(256) void k_gemm_mfma(const void* __restrict__ A_,
                                                   const unsigned short* __restrict__ Wb,
                                                   const float* __restrict__ bias,
                                                   const float* __restrict__ scale,
                                                   void* __restrict__ Cout, int M) {
    int wave = threadIdx.x >> 6, lane = threadIdx.x & 63;
    int quad = lane >> 4, r16 = lane & 15;
    int node0 = blockIdx.x * 64 + wave * 16;

    int arow = node0 + r16;
    if (arow >= M) arow = M - 1;                 // clamp read; stores guarded

    bf16x8 af[4];
    if (A_F32) {
        const float* Ap = (const float*)A_ + (size_t)arow * 128 + quad * 8;
#pragma unroll
        for (int ks = 0; ks < 4; ks++) {
            float4 x0 = *(const float4*)(Ap + ks * 32);
            float4 x1 = *(const float4*)(Ap + ks * 32 + 4);
            bf16x8 t;
            t[0] = (short)f2bf(x0.x); t[1] = (short)f2bf(x0.y);
            t[2] = (short)f2bf(x0.z); t[3] = (short)f2bf(x0.w);
            t[4] = (short)f2bf(x1.x); t[5] = (short)f2bf(x1.y);
            t[6] = (short)f2bf(x1.z); t[7] = (short)f2bf(x1.w);
            af[ks] = t;
        }
    } else {
        const unsigned short* Ap = (const unsigned short*)A_ + (size_t)arow * 128 + quad * 8;
#pragma unroll
        for (int ks = 0; ks < 4; ks++) af[ks] = *(const bf16x8*)(Ap + ks * 32);
    }

    // per-output-row scale factors (same 4 rows for every ft iteration)
    float dsc[4];
#pragma unroll
    for (int rg = 0; rg < 4; rg++) {
        int node = node0 + quad * 4 + rg;
        dsc[rg] = SCALE ? scale[(node < M) ? node : (M - 1)] : 1.f;
    }

    constexpr int NFT = F / 16;
#pragma unroll
    for (int ft = 0; ft < NFT; ft++) {
        int f = ft * 16 + r16;
        const unsigned short* Bp = Wb + (size_t)f * 128 + quad * 8;
        floatx4 acc = {0.f, 0.f, 0.f, 0.f};
#pragma unroll
        for (int ks = 0; ks < 4; ks++) {
            bf16x8 bfr = *(const bf16x8*)(Bp + ks * 32);
            acc = __builtin_amdgcn_mfma_f32_16x16x32_bf16(af[ks], bfr, acc, 0, 0, 0);
        }
        float bv = bias ? bias[f] : 0.f;
#pragma unroll
        for (int rg = 0; rg < 4; rg++) {
            int node = node0 + quad * 4 + rg;
            if (node < M) {
                float o = acc[rg];
                if (SCALE) o *= dsc[rg];
                o += bv;
                if (OUT_BF16)
                    ((unsigned short*)Cout)[(size_t)node * F + f] = f2bf(o);
                else
                    ((float*)Cout)[(size_t)node * F + f] = o;
            }
        }
    }
}

// ---------------- aggregation ------------------------------------------------
// m is pre-scaled by dis[src] ("m'"). One wave per node; lane owns 8 features
// (16B); 16 lanes cover a 256B row. Burst-32: edges 0..15 issue, then under a
// WAVE-UNIFORM branch (c is per-node) edges 16..31 issue before any unpacking
// -> up to 8 row-gathers in one miss round-trip (99.99% of nodes, Poisson 16).
// Inactive slots gather the zero row (index NN). Tail loads hoisted.
// out = relu(dis[v] * (sum m'[s] + m'[v]) + bias) + res.

__device__ __forceinline__ void acc8(float* acc, const uint4& r) {
    acc[0] += bf2f_lo(r.x); acc[1] += bf2f_hi(r.x);
    acc[2] += bf2f_lo(r.y); acc[3] += bf2f_hi(r.y);
    acc[4] += bf2f_lo(r.z); acc[5] += bf2f_hi(r.z);
    acc[6] += bf2f_lo(r.w); acc[7] += bf2f_hi(r.w);
}

template <bool RES_F32>
__global__ __launch_bounds__(256) void k_agg(const unsigned short* __restrict__ m,
                                             const int2* __restrict__ rc,
                                             const int* __restrict__ csr,
                                             const float* __restrict__ dis,
                                             const float* __restrict__ bias,
                                             const void* __restrict__ res_,
                                             unsigned short* __restrict__ hout) {
    int wave = threadIdx.x >> 6;
    int lane = threadIdx.x & 63;
    int v = blockIdx.x * 4 + wave;
    if (v >= NN) return;
    int g = lane >> 4;            // edge slot within batch (0..3)
    int fl = (lane & 15) * 8;     // 8 features per lane

    int2 rcv = rc[v];
    int start = rcv.x;
    int c = rcv.y;

    // hoisted tail loads (independent of the gather loop)
    const size_t vrow = (size_t)v * 128 + fl;
    float dv = dis[v];
    uint4 mv = *(const uint4*)&m[vrow];
    float4 b0 = *(const float4*)&bias[fl];
    float4 b1 = *(const float4*)&bias[fl + 4];
    float rr[8];
    if (RES_F32) {
        const float* rp = (const float*)res_ + (size_t)v * 128 + fl;
        float4 q0 = *(const float4*)rp;
        float4 q1 = *(const float4*)(rp + 4);
        rr[0] = q0.x; rr[1] = q0.y; rr[2] = q0.z; rr[3] = q0.w;
        rr[4] = q1.x; rr[5] = q1.y; rr[6] = q1.z; rr[7] = q1.w;
    } else {
        uint4 rv = *(const uint4*)((const unsigned short*)res_ + vrow);
        rr[0] = bf2f_lo(rv.x); rr[1] = bf2f_hi(rv.x);
        rr[2] = bf2f_lo(rv.y); rr[3] = bf2f_hi(rv.y);
        rr[4] = bf2f_lo(rv.z); rr[5] = bf2f_hi(rv.z);
        rr[6] = bf2f_lo(rv.w); rr[7] = bf2f_hi(rv.w);
    }

    float acc[8];
#pragma unroll
    for (int j = 0; j < 8; j++) acc[j] = 0.f;

    // block A: edges 0..15 (4 gathers in flight)
    int sA0 = (g      < c) ? csr[start + g     ] : NN;
    int sA1 = (g + 4  < c) ? csr[start + g + 4 ] : NN;
    int sA2 = (g + 8  < c) ? csr[start + g + 8 ] : NN;
    int sA3 = (g + 12 < c) ? csr[start + g + 12] : NN;
    uint4 ra0 = *(const uint4*)&m[(size_t)sA0 * 128 + fl];
    uint4 ra1 = *(const uint4*)&m[(size_t)sA1 * 128 + fl];
    uint4 ra2 = *(const uint4*)&m[(size_t)sA2 * 128 + fl];
    uint4 ra3 = *(const uint4*)&m[(size_t)sA3 * 128 + fl];

    if (c > 16) {   // wave-uniform: c is per-node
        // block B: edges 16..31 issue BEFORE unpacking block A -> 8 in flight
        int sB0 = (g + 16 < c) ? csr[start + g + 16] : NN;
        int sB1 = (g + 20 < c) ? csr[start + g + 20] : NN;
        int sB2 = (g + 24 < c) ? csr[start + g + 24] : NN;
        int sB3 = (g + 28 < c) ? csr[start + g + 28] : NN;
        uint4 rb0 = *(const uint4*)&m[(size_t)sB0 * 128 + fl];
        uint4 rb1 = *(const uint4*)&m[(size_t)sB1 * 128 + fl];
        uint4 rb2 = *(const uint4*)&m[(size_t)sB2 * 128 + fl];
        uint4 rb3 = *(const uint4*)&m[(size_t)sB3 * 128 + fl];
        acc8(acc, ra0); acc8(acc, ra1); acc8(acc, ra2); acc8(acc, ra3);
        acc8(acc, rb0); acc8(acc, rb1); acc8(acc, rb2); acc8(acc, rb3);
        for (int base = 32; base < c; base += 16) {
            int i0 = base + g, i1 = base + 4 + g, i2 = base + 8 + g, i3 = base + 12 + g;
            int s0 = (i0 < c) ? csr[start + i0] : NN;
            int s1 = (i1 < c) ? csr[start + i1] : NN;
            int s2 = (i2 < c) ? csr[start + i2] : NN;
            int s3 = (i3 < c) ? csr[start + i3] : NN;
            uint4 r0 = *(const uint4*)&m[(size_t)s0 * 128 + fl];
            uint4 r1 = *(const uint4*)&m[(size_t)s1 * 128 + fl];
            uint4 r2 = *(const uint4*)&m[(size_t)s2 * 128 + fl];
            uint4 r3 = *(const uint4*)&m[(size_t)s3 * 128 + fl];
            acc8(acc, r0); acc8(acc, r1); acc8(acc, r2); acc8(acc, r3);
        }
    } else {
        acc8(acc, ra0); acc8(acc, ra1); acc8(acc, ra2); acc8(acc, ra3);
    }

    // reduce the 4 lane-groups (XOR bits 5 and 4 of lane id)
#pragma unroll
    for (int j = 0; j < 8; j++) {
        acc[j] += __shfl_xor(acc[j], 32);
        acc[j] += __shfl_xor(acc[j], 16);
    }

    // tail: self-loop (m'[v]) + dis[v] scale + bias + relu + residual
    float mvf[8] = {bf2f_lo(mv.x), bf2f_hi(mv.x), bf2f_lo(mv.y), bf2f_hi(mv.y),
                    bf2f_lo(mv.z), bf2f_hi(mv.z), bf2f_lo(mv.w), bf2f_hi(mv.w)};
    float bb[8] = {b0.x, b0.y, b0.z, b0.w, b1.x, b1.y, b1.z, b1.w};
    unsigned short po[8];
#pragma unroll
    for (int j = 0; j < 8; j++) {
        float sum = acc[j] + mvf[j];
        float t = fmaxf(fmaf(sum, dv, bb[j]), 0.f) + rr[j];
        po[j] = f2bf(t);
    }
    if (g == 0) {
        uint4 o;
        o.x = (unsigned)po[0] | ((unsigned)po[1] << 16);
        o.y = (unsigned)po[2] | ((unsigned)po[3] << 16);
        o.z = (unsigned)po[4] | ((unsigned)po[5] << 16);
        o.w = (unsigned)po[6] | ((unsigned)po[7] << 16);
        *(uint4*)&hout[vrow] = o;
    }
}

// ---------------- host ----------------

extern "C" void kernel_launch(void* const* d_in, const int* in_sizes, int n_in,
                              void* d_out, int out_size, void* d_ws, size_t ws_size,
                              hipStream_t stream) {
    const float* x   = (const float*)d_in[0];
    const int*   ei  = (const int*)d_in[1];   // [2,E] int32
    const float* W1  = (const float*)d_in[2];
    const float* b1  = (const float*)d_in[3];
    const float* W2  = (const float*)d_in[4];
    const float* b2  = (const float*)d_in[5];
    const float* WL  = (const float*)d_in[6];
    const float* bl  = (const float*)d_in[7];
    float* out = (float*)d_out;

    const int* esrc = ei;
    const int* edst = ei + EE;

    char* w = (char*)d_ws;
    auto alloc = [&](size_t bytes) -> char* {
        char* p = w;
        w += (bytes + 255) & ~(size_t)255;
        return p;
    };
    int*   cntp    = (int*)alloc((size_t)NCOPY * NN * 4);  // 3.2MB XCD-local cursors
    int*   cnt     = (int*)alloc((size_t)NN * 4);
    int*   row_ptr = (int*)alloc((size_t)NN * 4);
    int2*  rc      = (int2*)alloc((size_t)NN * 8);
    float* dis     = (float*)alloc((size_t)NN * 4);
    int*   S       = (int*)alloc(1024 * 4);
    int*   rank    = (int*)alloc((size_t)EE * 4);
    int*   csr     = (int*)alloc((size_t)EE * 4);
    unsigned short* W1b = (unsigned short*)alloc(128 * 128 * 2);
    unsigned short* W2b = (unsigned short*)alloc(128 * 128 * 2);
    unsigned short* WLb = (unsigned short*)alloc(64 * 128 * 2);
    unsigned short* A   = (unsigned short*)alloc((size_t)(NN + 1) * 128 * 2);  // m' + zero row
    unsigned short* B   = (unsigned short*)alloc((size_t)NN * 128 * 2);        // h

    const int nb_n  = (NN + 255) / 256;
    const int nb_e8 = (EE / 8 + 255) / 256;   // 782
    const int nb_s1 = (NN + 1023) / 1024;     // 98

    // CSR build: XCD-local rank histogram -> fused prefix+scan -> no-atomic place
    k_zero_int4<<<(NCOPY * NN / 4 + 255) / 256, 256, 0, stream>>>((int4*)cntp, NCOPY * NN / 4);
    k_count_rank8<<<nb_e8, 256, 0, stream>>>(edst, cntp, rank);
    k_scan1<<<nb_s1, 1024, 0, stream>>>(cntp, cnt, row_ptr, S);
    k_scan2<<<1, 128, 0, stream>>>(S, nb_s1);
    k_scan3<<<nb_n, 256, 0, stream>>>(row_ptr, rc, S, cnt, dis, cntp,
                                      (unsigned int*)(A + (size_t)NN * 128));
    k_fill4<<<nb_e8, 256, 0, stream>>>(esrc, edst, rank, cntp, csr);

    // weights fp32 -> bf16 (single launch)
    k_cvt_w<<<40, 256, 0, stream>>>(W1, W2, WL, W1b, W2b, WLb);

    const int nb_g   = (NN + 63) / 64;     // 1563
    const int nb_agg = (NN + 3) / 4;       // 25000

    // layer 1: m1' = (x @ W1.T)*dis ; h1 = relu(dis*(sum+self)+b1) + x -> B
    k_gemm_mfma<128, true, true, true><<<nb_g, 256, 0, stream>>>(x, W1b, nullptr, dis, A, NN);
    k_agg<true><<<nb_agg, 256, 0, stream>>>(A, rc, csr, dis, b1, x, B);

    // layer 2: m2' = (h1 @ W2.T)*dis ; h2 = relu(...)+h1 -> B (in place)
    k_gemm_mfma<128, false, true, true><<<nb_g, 256, 0, stream>>>(B, W2b, nullptr, dis, A, NN);
    k_agg<false><<<nb_agg, 256, 0, stream>>>(A, rc, csr, dis, b2, B, B);

    // head: out = h2 @ Wlin.T + blin (fp32 out)
    k_gemm_mfma<64, false, false, false><<<nb_g, 256, 0, stream>>>(B, WLb, bl, nullptr, out, NN);
}

// Round 10
// 411.973 us; speedup vs baseline: 1.1034x; 1.1034x over previous
//
#include <hip/hip_runtime.h>

#define NN 100000
#define EE 1600000
#define NCOPY 8

typedef short bf16x8 __attribute__((ext_vector_type(8)));
typedef float floatx4 __attribute__((ext_vector_type(4)));

__device__ __forceinline__ unsigned short f2bf(float f) {
    unsigned int u = __float_as_uint(f);
    u = (u + 0x7FFF + ((u >> 16) & 1)) >> 16;   // round-to-nearest-even
    return (unsigned short)u;
}
__device__ __forceinline__ float bf2f_lo(unsigned int packed) {
    return __uint_as_float(packed << 16);
}
__device__ __forceinline__ float bf2f_hi(unsigned int packed) {
    return __uint_as_float(packed & 0xFFFF0000u);
}

// ---------------- init: zero cntp (782 blocks) + weight cvt (40 blocks) ------

#define ZB 782   // (NCOPY*NN/4 + 255)/256

__global__ __launch_bounds__(256) void k_init(int4* __restrict__ cntp4,
                                              const float* __restrict__ W1,
                                              const float* __restrict__ W2,
                                              const float* __restrict__ WL,
                                              unsigned short* __restrict__ W1b,
                                              unsigned short* __restrict__ W2b,
                                              unsigned short* __restrict__ WLb) {
    if (blockIdx.x < ZB) {
        int i = blockIdx.x * 256 + threadIdx.x;
        if (i < NCOPY * NN / 4) cntp4[i] = make_int4(0, 0, 0, 0);
        return;
    }
    int i = (blockIdx.x - ZB) * 256 + threadIdx.x;   // quad index
    const float* src; unsigned short* dst; int off;
    if (i < 4096)       { src = W1; dst = W1b; off = i; }
    else if (i < 8192)  { src = W2; dst = W2b; off = i - 4096; }
    else if (i < 10240) { src = WL; dst = WLb; off = i - 8192; }
    else return;
    float4 f = ((const float4*)src)[off];
    unsigned short r0 = f2bf(f.x), r1 = f2bf(f.y), r2 = f2bf(f.z), r3 = f2bf(f.w);
    ((ushort2*)dst)[off * 2]     = make_ushort2(r0, r1);
    ((ushort2*)dst)[off * 2 + 1] = make_ushort2(r2, r3);
}

// Pass 1: rank within XCD-local copy (p = blockIdx&7). Returning atomics, but
// copies kill cross-XCD line ping-pong; rank store is coalesced write-only.
__global__ void k_count_rank8(const int* __restrict__ dst, int* __restrict__ cntp,
                              int* __restrict__ rank) {
    int e8 = (blockIdx.x * 256 + threadIdx.x) * 8;
    int* c = cntp + (blockIdx.x & (NCOPY - 1)) * NN;
    if (e8 < EE) {   // EE % 8 == 0
        int4 d0 = *(const int4*)&dst[e8];
        int4 d1 = *(const int4*)&dst[e8 + 4];
        int4 r0, r1;
        r0.x = atomicAdd(&c[d0.x], 1);
        r0.y = atomicAdd(&c[d0.y], 1);
        r0.z = atomicAdd(&c[d0.z], 1);
        r0.w = atomicAdd(&c[d0.w], 1);
        r1.x = atomicAdd(&c[d1.x], 1);
        r1.y = atomicAdd(&c[d1.y], 1);
        r1.z = atomicAdd(&c[d1.z], 1);
        r1.w = atomicAdd(&c[d1.w], 1);
        *(int4*)&rank[e8]     = r0;
        *(int4*)&rank[e8 + 4] = r1;
    }
}

// scan1: per-node copy-prefix across the 8 cntp copies + 1024-block exclusive
// scan of totals; block totals -> S.
__global__ __launch_bounds__(1024) void k_scan1(int* __restrict__ cntp,
                                                int* __restrict__ cnt,
                                                int* __restrict__ row_ptr,
                                                int* __restrict__ S) {
    __shared__ int sh[1024];
    int tid = threadIdx.x;
    int i = blockIdx.x * 1024 + tid;
    int v = 0;
    if (i < NN) {
        int s = 0;
#pragma unroll
        for (int p = 0; p < NCOPY; p++) {
            int t = cntp[p * NN + i];
            cntp[p * NN + i] = s;    // within-node prefix across copies
            s += t;
        }
        cnt[i] = s;
        v = s;
    }
    sh[tid] = v;
    __syncthreads();
    for (int off = 1; off < 1024; off <<= 1) {
        int t = (tid >= off) ? sh[tid - off] : 0;
        __syncthreads();
        sh[tid] += t;
        __syncthreads();
    }
    if (i < NN) row_ptr[i] = sh[tid] - v;       // exclusive
    if (tid == 1023) S[blockIdx.x] = sh[tid];   // block total
}

// scan2+scan3 fused: every block redundantly scans the 98 block totals in LDS,
// then finalizes rc/dis and folds absolute row_ptr into the 8 copy cursors.
__global__ __launch_bounds__(256) void k_scan23(const int* __restrict__ row_ptr,
                                                int2* __restrict__ rc,
                                                const int* __restrict__ Sraw, int nb,
                                                const int* __restrict__ cnt,
                                                float* __restrict__ dis,
                                                int* __restrict__ cntp,
                                                unsigned int* __restrict__ Azero) {
    __shared__ int sh[128];
    int tid = threadIdx.x;
    int v = 0;
    if (tid < 128) {
        v = (tid < nb) ? Sraw[tid] : 0;
        sh[tid] = v;
    }
    __syncthreads();
    for (int off = 1; off < 128; off <<= 1) {
        int t = 0;
        if (tid < 128 && tid >= off) t = sh[tid - off];
        __syncthreads();
        if (tid < 128) sh[tid] += t;
        __syncthreads();
    }
    int excl = 0;
    if (tid < 128) excl = sh[tid] - v;
    __syncthreads();
    if (tid < 128) sh[tid] = excl;
    __syncthreads();

    int i = blockIdx.x * 256 + tid;
    if (i < NN) {
        int c = cnt[i];
        int r = row_ptr[i] + sh[i >> 10];
        rc[i] = make_int2(r, c);
        dis[i] = rsqrtf((float)(c + 1));
#pragma unroll
        for (int p = 0; p < NCOPY; p++) cntp[p * NN + i] += r;  // absolute base cursors
    }
    if (blockIdx.x == 0 && tid < 64) Azero[tid] = 0;  // 256B zero row
}

// ---------------- MFMA GEMM body (shared by standalone + packed kernels) -----
// C[M,F] = A[M,128] @ W[F,128].T, optional row scale (folds dis[src] in).
// Layouts (learn_hip m89): A[m=lane&15][k=quad*8+j], B[n=lane&15][k=quad*8+j],
// C/D col=lane&15 row=quad*4+reg.

template <int F, bool A_F32, bool OUT_BF16, bool SCALE>
__device__ __forceinline__ void gemm_body(int blk, int tid,
                                          const void* __restrict__ A_,
                                          const unsigned short* __restrict__ Wb,
                                          const float* __restrict__ bias,
                                          const float* __restrict__ scale,
                                          void* __restrict__ Cout, int M) {
    int wave = tid >> 6, lane = tid & 63;
    int quad = lane >> 4, r16 = lane & 15;
    int node0 = blk * 64 + wave * 16;

    int arow = node0 + r16;
    if (arow >= M) arow = M - 1;                 // clamp read; stores guarded

    bf16x8 af[4];
    if (A_F32) {
        const float* Ap = (const float*)A_ + (size_t)arow * 128 + quad * 8;
#pragma unroll
        for (int ks = 0; ks < 4; ks++) {
            float4 x0 = *(const float4*)(Ap + ks * 32);
            float4 x1 = *(const float4*)(Ap + ks * 32 + 4);
            bf16x8 t;
            t[0] = (short)f2bf(x0.x); t[1] = (short)f2bf(x0.y);
            t[2] = (short)f2bf(x0.z); t[3] = (short)f2bf(x0.w);
            t[4] = (short)f2bf(x1.x); t[5] = (short)f2bf(x1.y);
            t[6] = (short)f2bf(x1.z); t[7] = (short)f2bf(x1.w);
            af[ks] = t;
        }
    } else {
        const unsigned short* Ap = (const unsigned short*)A_ + (size_t)arow * 128 + quad * 8;
#pragma unroll
        for (int ks = 0; ks < 4; ks++) af[ks] = *(const bf16x8*)(Ap + ks * 32);
    }

    float dsc[4];
#pragma unroll
    for (int rg = 0; rg < 4; rg++) {
        int node = node0 + quad * 4 + rg;
        dsc[rg] = SCALE ? scale[(node < M) ? node : (M - 1)] : 1.f;
    }

    constexpr int NFT = F / 16;
#pragma unroll
    for (int ft = 0; ft < NFT; ft++) {
        int f = ft * 16 + r16;
        const unsigned short* Bp = Wb + (size_t)f * 128 + quad * 8;
        floatx4 acc = {0.f, 0.f, 0.f, 0.f};
#pragma unroll
        for (int ks = 0; ks < 4; ks++) {
            bf16x8 bfr = *(const bf16x8*)(Bp + ks * 32);
            acc = __builtin_amdgcn_mfma_f32_16x16x32_bf16(af[ks], bfr, acc, 0, 0, 0);
        }
        float bv = bias ? bias[f] : 0.f;
#pragma unroll
        for (int rg = 0; rg < 4; rg++) {
            int node = node0 + quad * 4 + rg;
            if (node < M) {
                float o = acc[rg];
                if (SCALE) o *= dsc[rg];
                o += bv;
                if (OUT_BF16)
                    ((unsigned short*)Cout)[(size_t)node * F + f] = f2bf(o);
                else
                    ((float*)Cout)[(size_t)node * F + f] = o;
            }
        }
    }
}

template <int F, bool A_F32, bool OUT_BF16, bool SCALE>
__global__ __launch_bounds__(256) void k_gemm_mfma(const void* __restrict__ A_,
                                                   const unsigned short* __restrict__ Wb,
                                                   const float* __restrict__ bias,
                                                   const float* __restrict__ scale,
                                                   void* __restrict__ Cout, int M) {
    gemm_body<F, A_F32, OUT_BF16, SCALE>(blockIdx.x, threadIdx.x, A_, Wb, bias, scale, Cout, M);
}

// ---------------- packed: fill4 (blocks 0..781) + GEMM1 (rest) ---------------
// fill4: place with NO atomics. slot = cpre[p][d] (plain gather) + rank[e].
// p-mapping (blk & 7) matches k_count_rank8's grid exactly.
// gemm1: m1' = (x @ W1.T)*dis  (independent of fill4; co-resident for overlap)

#define FB 782   // fill blocks

__global__ __launch_bounds__(256) void k_pack1(const int* __restrict__ src,
                                               const int* __restrict__ dst,
                                               const int* __restrict__ rank,
                                               const int* __restrict__ cntp,
                                               int* __restrict__ csr,
                                               const float* __restrict__ x,
                                               const unsigned short* __restrict__ W1b,
                                               const float* __restrict__ dis,
                                               unsigned short* __restrict__ A) {
    if (blockIdx.x < FB) {
        int e8 = (blockIdx.x * 256 + threadIdx.x) * 8;
        const int* c = cntp + (blockIdx.x & (NCOPY - 1)) * NN;
        if (e8 < EE) {
            int4 s0 = *(const int4*)&src[e8];
            int4 s1 = *(const int4*)&src[e8 + 4];
            int4 d0 = *(const int4*)&dst[e8];
            int4 d1 = *(const int4*)&dst[e8 + 4];
            int4 r0 = *(const int4*)&rank[e8];
            int4 r1 = *(const int4*)&rank[e8 + 4];
            csr[c[d0.x] + r0.x] = s0.x;
            csr[c[d0.y] + r0.y] = s0.y;
            csr[c[d0.z] + r0.z] = s0.z;
            csr[c[d0.w] + r0.w] = s0.w;
            csr[c[d1.x] + r1.x] = s1.x;
            csr[c[d1.y] + r1.y] = s1.y;
            csr[c[d1.z] + r1.z] = s1.z;
            csr[c[d1.w] + r1.w] = s1.w;
        }
        return;
    }
    gemm_body<128, true, true, true>(blockIdx.x - FB, threadIdx.x, x, W1b,
                                     nullptr, dis, A, NN);
}

// ---------------- aggregation (R7-proven: 4 gathers in flight, 28 VGPR) ------
// m is pre-scaled by dis[src] ("m'"). One wave per node; lane owns 8 features
// (16B); 16 lanes cover a 256B row; batch of 16 edges -> 4 independent gathers
// per lane-group per iteration. Inactive slots gather the zero row (index NN).
// out = relu(dis[v] * (sum m'[s] + m'[v]) + bias) + res.

template <bool RES_F32>
__global__ __launch_bounds__(256) void k_agg(const unsigned short* __restrict__ m,
                                             const int2* __restrict__ rc,
                                             const int* __restrict__ csr,
                                             const float* __restrict__ dis,
                                             const float* __restrict__ bias,
                                             const void* __restrict__ res_,
                                             unsigned short* __restrict__ hout) {
    int wave = threadIdx.x >> 6;
    int lane = threadIdx.x & 63;
    int v = blockIdx.x * 4 + wave;
    if (v >= NN) return;
    int g = lane >> 4;            // edge slot within batch (0..3)
    int fl = (lane & 15) * 8;     // 8 features per lane

    float acc[8];
#pragma unroll
    for (int j = 0; j < 8; j++) acc[j] = 0.f;

    int2 rcv = rc[v];
    int start = rcv.x;
    int c = rcv.y;

    for (int base = 0; base < c; base += 16) {
        int i0 = base + g, i1 = base + 4 + g, i2 = base + 8 + g, i3 = base + 12 + g;
        bool p0 = i0 < c, p1 = i1 < c, p2 = i2 < c, p3 = i3 < c;
        int s0 = csr[start + (p0 ? i0 : 0)];
        int s1 = csr[start + (p1 ? i1 : 0)];
        int s2 = csr[start + (p2 ? i2 : 0)];
        int s3 = csr[start + (p3 ? i3 : 0)];
        if (!p0) s0 = NN;          // zero row
        if (!p1) s1 = NN;
        if (!p2) s2 = NN;
        if (!p3) s3 = NN;
        uint4 r0 = *(const uint4*)&m[(size_t)s0 * 128 + fl];
        uint4 r1 = *(const uint4*)&m[(size_t)s1 * 128 + fl];
        uint4 r2 = *(const uint4*)&m[(size_t)s2 * 128 + fl];
        uint4 r3 = *(const uint4*)&m[(size_t)s3 * 128 + fl];
#pragma unroll
        for (int q = 0; q < 4; q++) {
            uint4 r = q == 0 ? r0 : q == 1 ? r1 : q == 2 ? r2 : r3;
            acc[0] += bf2f_lo(r.x);
            acc[1] += bf2f_hi(r.x);
            acc[2] += bf2f_lo(r.y);
            acc[3] += bf2f_hi(r.y);
            acc[4] += bf2f_lo(r.z);
            acc[5] += bf2f_hi(r.z);
            acc[6] += bf2f_lo(r.w);
            acc[7] += bf2f_hi(r.w);
        }
    }

    // reduce the 4 lane-groups (XOR bits 5 and 4 of lane id)
#pragma unroll
    for (int j = 0; j < 8; j++) {
        acc[j] += __shfl_xor(acc[j], 32);
        acc[j] += __shfl_xor(acc[j], 16);
    }

    // tail: self-loop (m'[v]) + dis[v] scale + bias + relu + residual
    const size_t vrow = (size_t)v * 128 + fl;
    float dv = dis[v];
    uint4 mv = *(const uint4*)&m[vrow];
    float4 b0 = *(const float4*)&bias[fl];
    float4 b1 = *(const float4*)&bias[fl + 4];
    float mvf[8] = {bf2f_lo(mv.x), bf2f_hi(mv.x), bf2f_lo(mv.y), bf2f_hi(mv.y),
                    bf2f_lo(mv.z), bf2f_hi(mv.z), bf2f_lo(mv.w), bf2f_hi(mv.w)};
    float bb[8] = {b0.x, b0.y, b0.z, b0.w, b1.x, b1.y, b1.z, b1.w};
    float rr[8];
    if (RES_F32) {
        const float* rp = (const float*)res_ + (size_t)v * 128 + fl;
        float4 q0 = *(const float4*)rp;
        float4 q1 = *(const float4*)(rp + 4);
        rr[0] = q0.x; rr[1] = q0.y; rr[2] = q0.z; rr[3] = q0.w;
        rr[4] = q1.x; rr[5] = q1.y; rr[6] = q1.z; rr[7] = q1.w;
    } else {
        uint4 rv = *(const uint4*)((const unsigned short*)res_ + vrow);
        rr[0] = bf2f_lo(rv.x); rr[1] = bf2f_hi(rv.x);
        rr[2] = bf2f_lo(rv.y); rr[3] = bf2f_hi(rv.y);
        rr[4] = bf2f_lo(rv.z); rr[5] = bf2f_hi(rv.z);
        rr[6] = bf2f_lo(rv.w); rr[7] = bf2f_hi(rv.w);
    }
    unsigned short po[8];
#pragma unroll
    for (int j = 0; j < 8; j++) {
        float sum = acc[j] + mvf[j];
        float t = fmaxf(fmaf(sum, dv, bb[j]), 0.f) + rr[j];
        po[j] = f2bf(t);
    }
    if (g == 0) {
        uint4 o;
        o.x = (unsigned)po[0] | ((unsigned)po[1] << 16);
        o.y = (unsigned)po[2] | ((unsigned)po[3] << 16);
        o.z = (unsigned)po[4] | ((unsigned)po[5] << 16);
        o.w = (unsigned)po[6] | ((unsigned)po[7] << 16);
        *(uint4*)&hout[vrow] = o;
    }
}

// ---------------- host ----------------

extern "C" void kernel_launch(void* const* d_in, const int* in_sizes, int n_in,
                              void* d_out, int out_size, void* d_ws, size_t ws_size,
                              hipStream_t stream) {
    const float* x   = (const float*)d_in[0];
    const int*   ei  = (const int*)d_in[1];   // [2,E] int32
    const float* W1  = (const float*)d_in[2];
    const float* b1  = (const float*)d_in[3];
    const float* W2  = (const float*)d_in[4];
    const float* b2  = (const float*)d_in[5];
    const float* WL  = (const float*)d_in[6];
    const float* bl  = (const float*)d_in[7];
    float* out = (float*)d_out;

    const int* esrc = ei;
    const int* edst = ei + EE;

    char* w = (char*)d_ws;
    auto alloc = [&](size_t bytes) -> char* {
        char* p = w;
        w += (bytes + 255) & ~(size_t)255;
        return p;
    };
    int*   cntp    = (int*)alloc((size_t)NCOPY * NN * 4);  // 3.2MB XCD-local cursors
    int*   cnt     = (int*)alloc((size_t)NN * 4);
    int*   row_ptr = (int*)alloc((size_t)NN * 4);
    int2*  rc      = (int2*)alloc((size_t)NN * 8);
    float* dis     = (float*)alloc((size_t)NN * 4);
    int*   S       = (int*)alloc(1024 * 4);
    int*   rank    = (int*)alloc((size_t)EE * 4);
    int*   csr     = (int*)alloc((size_t)EE * 4);
    unsigned short* W1b = (unsigned short*)alloc(128 * 128 * 2);
    unsigned short* W2b = (unsigned short*)alloc(128 * 128 * 2);
    unsigned short* WLb = (unsigned short*)alloc(64 * 128 * 2);
    unsigned short* A   = (unsigned short*)alloc((size_t)(NN + 1) * 128 * 2);  // m' + zero row
    unsigned short* B   = (unsigned short*)alloc((size_t)NN * 128 * 2);        // h

    const int nb_e8 = (EE / 8 + 255) / 256;   // 782 == FB == count grid
    const int nb_s1 = (NN + 1023) / 1024;     // 98
    const int nb_s23 = (NN + 255) / 256;      // 391

    // init: zero cntp + weight converts (one packed launch)
    k_init<<<ZB + 40, 256, 0, stream>>>((int4*)cntp, W1, W2, WL, W1b, W2b, WLb);
    // rank histogram into XCD-local copies
    k_count_rank8<<<nb_e8, 256, 0, stream>>>(edst, cntp, rank);
    // copy-prefix + block scan; then fused S-scan + finalize
    k_scan1<<<nb_s1, 1024, 0, stream>>>(cntp, cnt, row_ptr, S);
    k_scan23<<<nb_s23, 256, 0, stream>>>(row_ptr, rc, S, nb_s1, cnt, dis, cntp,
                                         (unsigned int*)(A + (size_t)NN * 128));
    // packed: CSR place (no atomics) + GEMM1 (m1' = (x@W1.T)*dis) overlap
    k_pack1<<<FB + (NN + 63) / 64, 256, 0, stream>>>(esrc, edst, rank, cntp, csr,
                                                     x, W1b, dis, A);

    const int nb_g   = (NN + 63) / 64;     // 1563
    const int nb_agg = (NN + 3) / 4;       // 25000

    // layer 1 agg: h1 = relu(dis*(sum+self)+b1) + x -> B
    k_agg<true><<<nb_agg, 256, 0, stream>>>(A, rc, csr, dis, b1, x, B);

    // layer 2: m2' = (h1 @ W2.T)*dis ; h2 = relu(...)+h1 -> B (in place)
    k_gemm_mfma<128, false, true, true><<<nb_g, 256, 0, stream>>>(B, W2b, nullptr, dis, A, NN);
    k_agg<false><<<nb_agg, 256, 0, stream>>>(A, rc, csr, dis, b2, B, B);

    // head: out = h2 @ Wlin.T + blin (fp32 out)
    k_gemm_mfma<64, false, false, false><<<nb_g, 256, 0, stream>>>(B, WLb, bl, nullptr, out, NN);
}